// Round 13
// baseline (127.265 us; speedup 1.0000x reference)
//
#include <hip/hip_runtime.h>
#include <hip/hip_bf16.h>
#include <cstddef>
#include <cstring>

// ---------------- problem dims (hard-coded from reference) ----------------
constexpr int cB=4, cN=2000, cT=50, cF=10, cD=64, cR=8, cK=16, cE=32;
constexpr int NODES = cB*cN;     // 8000
constexpr int N1    = cN+1;      // 2001 (padded table incl. zero row m=0)
constexpr int ROWS2 = cB*N1;     // 8004
constexpr int PT    = 8;                      // row-tiles per k_proj block
constexpr int PBLK  = (501 + PT - 1)/PT;      // 63 blocks per r

#define DEV static __device__ __forceinline__

typedef __attribute__((ext_vector_type(8))) _Float16 f16x8;   // 8 f16 = 4 VGPR
typedef __attribute__((ext_vector_type(4))) float    f32x4;
typedef __attribute__((ext_vector_type(4))) int      i32x4;

DEV float leaky(float x){ return fmaxf(x, 0.2f*x); }
DEV float wsumall(float v){           // butterfly all-reduce over 64 lanes
  v += __shfl_xor(v,32,64); v += __shfl_xor(v,16,64); v += __shfl_xor(v,8,64);
  v += __shfl_xor(v,4,64);  v += __shfl_xor(v,2,64);  v += __shfl_xor(v,1,64);
  return v;
}
DEV unsigned fu(float f){ return __float_as_uint(f); }
DEV unsigned rne16(float f){                      // RNE bf16 bits of f
  unsigned u = fu(f);
  return (u + 0x7FFFu + ((u>>16)&1u)) >> 16;
}
DEV unsigned f16b(float f){                       // f32 -> f16 bits (RNE)
  _Float16 h = (_Float16)f;
  unsigned short u; __builtin_memcpy(&u, &h, 2);
  return (unsigned)u;
}
DEV unsigned f16p(float a, float b){ return f16b(a) | (f16b(b) << 16); }
DEV void split16(float f, unsigned &hi, unsigned &lo){  // f ~= f16(hi) + f16(lo)
  _Float16 h = (_Float16)f;
  float r = f - (float)h;
  _Float16 l = (_Float16)r;
  unsigned short uh, ul;
  __builtin_memcpy(&uh, &h, 2); __builtin_memcpy(&ul, &l, 2);
  hi = uh; lo = ul;
}
DEV f16x8 packh(unsigned a, unsigned b, unsigned c2, unsigned d){
  union { i32x4 i; f16x8 h; } u;
  u.i = (i32x4){(int)a,(int)b,(int)c2,(int)d};
  return u.h;
}
DEV f16x8 asf16(i32x4 v){
  union { i32x4 i; f16x8 h; } u; u.i = v; return u.h;
}
DEV f32x4 MF16(f16x8 a, f16x8 b, f32x4 c){
  return __builtin_amdgcn_mfma_f32_16x16x32_f16(a, b, c, 0, 0, 0);
}
DEV float bfu(unsigned short u){ return __uint_as_float(((unsigned)u)<<16); }
DEV float ex2(float x){ float r; asm("v_exp_f32 %0, %1" : "=v"(r) : "v"(x)); return r; }

// ====== K1: GRU — solo wave per 16-node tile, h as f16 hi/lo split =========
// Block = 64 thr = 1 wave owning a full 16-node tile: 12 col-blocks of 16
// gate columns; per cb: 3 x-MFMA + 12 h-MFMA (hi+lo halves) + 4 fused
// gates/lane -> 60 MFMA/step. U (f16, scaled) lives in 96 VGPR; W in 48.
// h crosses steps via wave-private double-buffered XOR-swizzled f16 LDS
// tiles (hi + residual lo -> h error ~2^-22; output floor = bf16 2e-3).
// Step fence = __syncthreads() — the compiler-respected fence every passing
// round used (R12's asm-only lgkmcnt fence allowed reordering -> 2.5e-2).
// For a lone wave the barrier is ~free; the vmcnt drain only waits on a
// prefetch issued one full step earlier (L2-resident X).
__global__ __launch_bounds__(64) void k_gru(const float* __restrict__ X,
    const float* __restrict__ gW, const float* __restrict__ gU,
    const float* __restrict__ gb, float* __restrict__ node)
{
  __shared__ unsigned sHh[2][512];  // hi  tile: [(node*32 + d/2) ^ ((node&7)<<2)]
  __shared__ unsigned sHl[2][512];  // lo (residual) tile, same layout

  const int lane = threadIdx.x;     // 0..63
  const int c    = lane & 15;       // A-row (node) / col-within-block
  const int kg   = lane >> 4;       // k-group
  const int nb   = (int)blockIdx.x * 16;

  const float SZ = -1.4426950408889634f;   // -log2(e): z,r gates
  const float SH =  2.8853900817779268f;   // 2*log2(e): h~ gate

  // ---- persistent B fragments: entire U (f16, scaled) = 96 VGPR ----
  f16x8 Uf[2][3][4];
  #pragma unroll
  for (int s=0;s<2;++s){
    #pragma unroll
    for (int cls=0; cls<3; ++cls){
      const float sc = (cls==2) ? SH : SZ;
      #pragma unroll
      for (int cb=0; cb<4; ++cb){
        const int n = cls*64 + cb*16 + c;
        unsigned wd[4];
        #pragma unroll
        for (int p=0;p<4;++p){
          int d0 = s*32 + kg*8 + 2*p;
          wd[p] = f16p(sc*gU[d0*192 + n], sc*gU[(d0+1)*192 + n]);
        }
        Uf[s][cls][cb] = packh(wd[0],wd[1],wd[2],wd[3]);
      }
    }
  }
  // ---- W (f16, k=2f slots, lo16 only) + biases riding the f==10 slot ----
  f16x8 BX[3][4];
  #pragma unroll
  for (int cls=0; cls<3; ++cls){
    const float sc = (cls==2) ? SH : SZ;
    #pragma unroll
    for (int cb=0; cb<4; ++cb){
      const int n = cls*64 + cb*16 + c;
      const float bv = (cls==2) ? SH*gb[128 + cb*16 + c]
                                : SZ*(gb[n] + gb[192+n]);   // z: n=col, r: n=64+col
      unsigned wd[4];
      #pragma unroll
      for (int p=0;p<4;++p){
        int f = kg*4 + p;
        unsigned v = (f < cF) ? f16b(sc*gW[f*192 + n]) : ((f == cF) ? f16b(bv) : 0u);
        wd[p] = v;                      // hi16 = 0 (odd k-slots multiply zero)
      }
      BX[cls][cb] = packh(wd[0],wd[1],wd[2],wd[3]);
    }
  }
  // hc-gate U-side bias (init of aHc), per col-block
  float bh1v[4];
  #pragma unroll
  for (int cb=0; cb<4; ++cb) bh1v[cb] = SH*gb[320 + cb*16 + c];

  // ---- zero h buffers (buf 0, hi+lo) ----
  #pragma unroll
  for (int i2=0; i2<8; ++i2){ sHh[0][lane*8 + i2] = 0u; sHl[0][lane*8 + i2] = 0u; }
  float ho[16];
  #pragma unroll
  for (int i2=0; i2<16; ++i2) ho[i2] = 0.f;
  __syncthreads();

  // ---- x prefetch, 2 steps ahead; f==10 slot carries constant 1.0 ----
  float xc[4], xn[4];
  const float* Xb = X + (size_t)(nb + c)*cT*cF;
  #pragma unroll
  for (int p=0;p<4;++p){
    int f = 4*kg+p;
    float fill = (f == cF) ? 1.0f : 0.0f;
    xc[p] = (f < cF) ? Xb[0*cF + f] : fill;
    xn[p] = (f < cF) ? Xb[1*cF + f] : fill;
  }

  // ---- hoisted LDS offsets ----
  const unsigned sw2   = (unsigned)((c&7)<<2);
  const unsigned base0 = ((unsigned)(c*32 + kg*4))      ^ sw2;   // d 0..31
  const unsigned base1 = ((unsigned)(c*32 + 16 + kg*4)) ^ sw2;   // d 32..63
  unsigned hws[16];     // u16 index for h[node=kg*4+reg][d=16*cb+c]
  #pragma unroll
  for (int cb=0; cb<4; ++cb){
    #pragma unroll
    for (int reg=0; reg<4; ++reg){
      int nodei = kg*4 + reg;
      hws[cb*4+reg] =
        (((unsigned)(nodei*32 + 8*cb + (c>>1))) ^ ((unsigned)((nodei&7)<<2)))*2
        + (unsigned)(c&1);
    }
  }
  const f32x4 zq = {0.f,0.f,0.f,0.f};

  #pragma unroll 1
  for (int t = 0; t < cT; ++t){
    // ---- x A-fragment (f16 in lo16 of each dword; shared by all cb) ----
    f16x8 xf = packh(f16b(xc[0]), f16b(xc[1]), f16b(xc[2]), f16b(xc[3]));
    #pragma unroll
    for (int p=0;p<4;++p) xc[p] = xn[p];
    {
      int tn = (t+2 < cT) ? t+2 : cT-1;
      #pragma unroll
      for (int p=0;p<4;++p){
        int f = 4*kg+p;
        float fill = (f == cF) ? 1.0f : 0.0f;
        xn[p] = (f < cF) ? Xb[(size_t)tn*cF + f] : fill;
      }
    }

    // ---- h A-fragments (hi + lo, raw f16) ----
    const unsigned* srh = sHh[t & 1];
    const unsigned* srl = sHl[t & 1];
    i32x4 qh0 = *(const i32x4*)(srh + base0);
    i32x4 qh1 = *(const i32x4*)(srh + base1);
    i32x4 ql0 = *(const i32x4*)(srl + base0);
    i32x4 ql1 = *(const i32x4*)(srl + base1);
    f16x8 hah = asf16(qh0), hbh = asf16(qh1);
    f16x8 hal = asf16(ql0), hbl = asf16(ql1);

    unsigned short* swh = (unsigned short*)&sHh[(t & 1) ^ 1][0];
    unsigned short* swl = (unsigned short*)&sHl[(t & 1) ^ 1][0];

    // ---- per col-block: 15 MFMA + 4 fused gates (4 independent groups) ----
    #pragma unroll
    for (int cb=0; cb<4; ++cb){
      f32x4 aZ  = MF16(xf, BX[0][cb], zq);
      f32x4 aR  = MF16(xf, BX[1][cb], zq);
      f32x4 aXh = MF16(xf, BX[2][cb], zq);
      f32x4 aHc = {bh1v[cb],bh1v[cb],bh1v[cb],bh1v[cb]};
      aZ  = MF16(hah, Uf[0][0][cb], aZ);  aZ  = MF16(hbh, Uf[1][0][cb], aZ);
      aR  = MF16(hah, Uf[0][1][cb], aR);  aR  = MF16(hbh, Uf[1][1][cb], aR);
      aHc = MF16(hah, Uf[0][2][cb], aHc); aHc = MF16(hbh, Uf[1][2][cb], aHc);
      aZ  = MF16(hal, Uf[0][0][cb], aZ);  aZ  = MF16(hbl, Uf[1][0][cb], aZ);
      aR  = MF16(hal, Uf[0][1][cb], aR);  aR  = MF16(hbl, Uf[1][1][cb], aR);
      aHc = MF16(hal, Uf[0][2][cb], aHc); aHc = MF16(hbl, Uf[1][2][cb], aHc);
      #pragma unroll
      for (int reg=0; reg<4; ++reg){
        float z   = __builtin_amdgcn_rcpf(1.0f + ex2(aZ[reg]));
        float r   = __builtin_amdgcn_rcpf(1.0f + ex2(aR[reg]));
        float phv = __builtin_fmaf(r, aHc[reg], aXh[reg]);
        float th  = __builtin_fmaf(-2.0f, __builtin_amdgcn_rcpf(ex2(phv) + 1.0f), 1.0f);
        float hn  = __builtin_fmaf(z, ho[cb*4+reg]-th, th);
        ho[cb*4+reg] = hn;
        unsigned hi, lo; split16(hn, hi, lo);
        swh[hws[cb*4+reg]] = (unsigned short)hi;
        swl[hws[cb*4+reg]] = (unsigned short)lo;
      }
    }
    // full fence (compiler-respected): writes visible before next step's reads
    __syncthreads();
  }

  // ---- write out h (fp32) for k_proj / k_attn ----
  #pragma unroll
  for (int cb=0; cb<4; ++cb){
    #pragma unroll
    for (int reg=0; reg<4; ++reg)
      node[(size_t)(nb + kg*4 + reg)*cD + cb*16 + c] = ho[cb*4+reg];
  }
}

// ============ K2: projection table + sng (f16 MFMA, full occupancy) ========
// Block = 256 thr = 4 waves, one r, PT=8 row-tiles of the padded table.
// Wave w handles 2 tiles. A = f16(node fp32) == the recurrence's h-hi;
// m=0 rows fall out naturally (zeroed A-row -> act = leaky(bias)).
__global__ __launch_bounds__(256) void k_proj(const float* __restrict__ node,
    const float* __restrict__ pW, const float* __restrict__ pb,
    const float* __restrict__ sattW, unsigned short* __restrict__ actb,
    float* __restrict__ sng2)
{
  const int r  = (int)blockIdx.x / PBLK;
  const int t0 = ((int)blockIdx.x % PBLK) * PT;
  const int tid = threadIdx.x, w = tid>>6, lane = tid&63, c = lane&15, kg = lane>>4;

  // B fragments for this r (dense f16 pairs, k = d)
  const float* Pr = pW + (size_t)r*cD*cD;
  f16x8 PB[4][2];
  float pbv[4], wnv[4];
  #pragma unroll
  for (int cb=0; cb<4; ++cb){
    const int e = 16*cb + c;
    #pragma unroll
    for (int s2=0;s2<2;++s2){
      unsigned wd[4];
      #pragma unroll
      for (int p=0;p<4;++p){
        int d0 = s2*32 + kg*8 + 2*p;
        wd[p] = f16p(Pr[(size_t)d0*cD + e], Pr[(size_t)(d0+1)*cD + e]);
      }
      PB[cb][s2] = packh(wd[0],wd[1],wd[2],wd[3]);
    }
    pbv[cb] = pb[r*cD + e];
    wnv[cb] = sattW[r*(2*cD+cE) + cD + e];
  }

  #pragma unroll
  for (int tt=0; tt<2; ++tt){
    const int T  = t0 + w*2 + tt;
    const int q  = T*16 + c;                    // A-row of this lane
    int b = q / N1;
    bool valid = (q < ROWS2) && (q != b*N1);    // m=0 -> zero row
    int nrow = valid ? (q - b - 1) : 0;
    const float* arow = node + (size_t)nrow*cD;
    unsigned wa[4], wb[4];
    #pragma unroll
    for (int p=0;p<4;++p){
      float v0 = valid ? arow[kg*8 + 2*p]       : 0.f;
      float v1 = valid ? arow[kg*8 + 2*p + 1]   : 0.f;
      float v2 = valid ? arow[32 + kg*8 + 2*p]  : 0.f;
      float v3 = valid ? arow[32 + kg*8 + 2*p+1]: 0.f;
      wa[p] = f16p(v0, v1);
      wb[p] = f16p(v2, v3);
    }
    f16x8 ha = packh(wa[0],wa[1],wa[2],wa[3]);
    f16x8 hb = packh(wb[0],wb[1],wb[2],wb[3]);

    float sp[4] = {0.f,0.f,0.f,0.f};
    #pragma unroll
    for (int cb=0; cb<4; ++cb){
      f32x4 acc = {pbv[cb],pbv[cb],pbv[cb],pbv[cb]};
      acc = MF16(ha, PB[cb][0], acc);
      acc = MF16(hb, PB[cb][1], acc);
      #pragma unroll
      for (int reg=0; reg<4; ++reg){
        float o = leaky(acc[reg]);
        int qo = T*16 + kg*4 + reg;
        if (qo < ROWS2)
          actb[((size_t)r*ROWS2 + qo)*cD + 16*cb + c] = (unsigned short)rne16(o);
        sp[reg] = __builtin_fmaf(o, wnv[cb], sp[reg]);
      }
    }
    #pragma unroll
    for (int reg=0; reg<4; ++reg){
      float s2 = sp[reg];
      s2 += __shfl_xor(s2,1,64); s2 += __shfl_xor(s2,2,64);
      s2 += __shfl_xor(s2,4,64); s2 += __shfl_xor(s2,8,64);
      int qo = T*16 + kg*4 + reg;
      if (c == 0 && qo < ROWS2) sng2[(size_t)r*ROWS2 + qo] = s2;
    }
  }
}

// ============ K3: fused attention + head (+ per-r scalars), 1 wave/(b,n) ==
__global__ __launch_bounds__(256) void k_attn(const float* __restrict__ node,
    const int* __restrict__ nbrs, const float* __restrict__ sattW,
    const float* __restrict__ sattb, const float* __restrict__ rattW,
    const float* __restrict__ rattb, const float* __restrict__ predW,
    const float* __restrict__ predb, const float* __restrict__ relemb,
    const unsigned short* __restrict__ actb, const float* __restrict__ sng2,
    float* __restrict__ out)
{
  __shared__ float sSA[cR][cD];        // w_cur rows
  __shared__ float sSrel[cR], sRremb[cR];
  __shared__ float sAtt[4][cR][cK];
  __shared__ int   sOff[4][cR][cK];
  const int tid = threadIdx.x;
  for (int i=tid; i<cR*cD; i+=256) sSA[i>>6][i&63] = sattW[(i>>6)*(2*cD+cE) + (i&63)];
  if (tid < 64){                       // per-r scalars: srel, rremb
    int r = tid >> 3, j0 = (tid & 7)*4;
    float a = 0.f, b2 = 0.f;
    #pragma unroll
    for (int j=0;j<4;++j){
      float re = relemb[r*cE + j0 + j];
      a  += re * sattW[r*(2*cD+cE) + 2*cD + j0 + j];
      b2 += re * rattW[2*cD + j0 + j];
    }
    a  += __shfl_xor(a,1,64);  a  += __shfl_xor(a,2,64);  a  += __shfl_xor(a,4,64);
    b2 += __shfl_xor(b2,1,64); b2 += __shfl_xor(b2,2,64); b2 += __shfl_xor(b2,4,64);
    if ((tid & 7) == 0){ sSrel[r] = a + sattb[r]; sRremb[r] = b2; }
  }
  __syncthreads();

  const int wave = tid >> 6, lane = tid & 63;
  const int gn = (int)blockIdx.x*4 + wave;          // 0..7999
  const int b = __builtin_amdgcn_readfirstlane(gn / cN);
  const int n = __builtin_amdgcn_readfirstlane(gn % cN);

  const float cur = node[(size_t)gn*cD + lane];

  float scr[8];
  #pragma unroll
  for (int r=0; r<8; ++r) scr[r] = wsumall(cur * sSA[r][lane]);

  const int g = lane >> 4, k = lane & 15;
  #pragma unroll
  for (int half=0; half<2; ++half){
    int r = half*4 + g;
    float sc0 = half==0 ? (g==0?scr[0]:g==1?scr[1]:g==2?scr[2]:scr[3])
                        : (g==0?scr[4]:g==1?scr[5]:g==2?scr[6]:scr[7]);
    int idx = nbrs[(((size_t)b*cR + r)*cN + n)*cK + k];
    int o = r*ROWS2 + b*N1 + idx;
    float sv = sng2[o];
    float sc = leaky(sc0 + sv + sSrel[r]);
    if (idx == 0) sc -= 1e9f;
    float mx = sc;
    mx = fmaxf(mx, __shfl_xor(mx,1,64)); mx = fmaxf(mx, __shfl_xor(mx,2,64));
    mx = fmaxf(mx, __shfl_xor(mx,4,64)); mx = fmaxf(mx, __shfl_xor(mx,8,64));
    float ex = __expf(sc - mx);
    float sm = ex;
    sm += __shfl_xor(sm,1,64); sm += __shfl_xor(sm,2,64);
    sm += __shfl_xor(sm,4,64); sm += __shfl_xor(sm,8,64);
    sAtt[wave][r][k] = ex/sm;
    sOff[wave][r][k] = o;
  }
  __syncthreads();

  float facc[8];
  #pragma unroll
  for (int r=0; r<8; ++r){
    float a0=0.f, a1=0.f;
    #pragma unroll
    for (int kk=0; kk<cK; kk+=2){
      float w0 = sAtt[wave][r][kk],   w1 = sAtt[wave][r][kk+1];
      int   o0 = sOff[wave][r][kk],   o1 = sOff[wave][r][kk+1];
      a0 += w0 * bfu(actb[(size_t)o0*cD + lane]);
      a1 += w1 * bfu(actb[(size_t)o1*cD + lane]);
    }
    facc[r] = a0 + a1;
  }

  const float rcur = rattW[lane], rrep = rattW[cD + lane];
  const float rb   = rattb[0];
  const float c0 = wsumall(cur * rcur);
  float rs[8];
  #pragma unroll
  for (int r=0; r<8; ++r) rs[r] = leaky(c0 + wsumall(facc[r]*rrep) + sRremb[r] + rb);
  float mx = rs[0];
  #pragma unroll
  for (int r=1; r<8; ++r) mx = fmaxf(mx, rs[r]);
  float es = 0.f; float ratt[8];
  #pragma unroll
  for (int r=0; r<8; ++r){ ratt[r] = __expf(rs[r]-mx); es += ratt[r]; }
  float inv = 1.f/es;
  float agg = 0.f;
  #pragma unroll
  for (int r=0; r<8; ++r) agg += (ratt[r]*inv) * facc[r];
  const float upd = cur + agg;

  float l0 = wsumall(upd * predW[lane*3 + 0]);
  float l1 = wsumall(upd * predW[lane*3 + 1]);
  float l2 = wsumall(upd * predW[lane*3 + 2]);
  if (lane == 0){
    l0 += predb[0]; l1 += predb[1]; l2 += predb[2];
    float m2 = fmaxf(l0, fmaxf(l1, l2));
    float e0 = __expf(l0-m2), e1 = __expf(l1-m2), e2 = __expf(l2-m2);
    float is = 1.f/(e0+e1+e2);
    out[(size_t)gn*3+0] = e0*is;
    out[(size_t)gn*3+1] = e1*is;
    out[(size_t)gn*3+2] = e2*is;
  }
}

// ================================ launch =================================
extern "C" void kernel_launch(void* const* d_in, const int* in_sizes, int n_in,
                              void* d_out, int out_size, void* d_ws, size_t ws_size,
                              hipStream_t stream)
{
  const float* X      = (const float*)d_in[0];
  const int*   nbrs   = (const int*)  d_in[1];
  const float* gW     = (const float*)d_in[2];
  const float* gU     = (const float*)d_in[3];
  const float* gb     = (const float*)d_in[4];
  const float* relemb = (const float*)d_in[5];
  const float* pW     = (const float*)d_in[6];
  const float* pb     = (const float*)d_in[7];
  const float* sattW  = (const float*)d_in[8];
  const float* sattb  = (const float*)d_in[9];
  const float* rattW  = (const float*)d_in[10];
  const float* rattb  = (const float*)d_in[11];
  const float* predW  = (const float*)d_in[12];
  const float* predb  = (const float*)d_in[13];
  float* out = (float*)d_out;

  // workspace: node fp32 | act bf16 (r-major) | sng fp32
  float*          node  = (float*)d_ws;                                 // NODES*cD
  unsigned short* actb  = (unsigned short*)(node + (size_t)NODES*cD);   // cR*ROWS2*cD bf16
  float*          sng2  = (float*)(actb + (size_t)cR*ROWS2*cD);         // cR*ROWS2

  k_gru <<<NODES/16, 64, 0, stream>>>(X, gW, gU, gb, node);
  k_proj<<<cR*PBLK, 256, 0, stream>>>(node, pW, pb, sattW, actb, sng2);
  k_attn<<<NODES/4, 256, 0, stream>>>(node, nbrs, sattW, sattb, rattW, rattb,
                                      predW, predb, relemb, actb, sng2, out);
}

// Round 16
// 88.416 us; speedup vs baseline: 1.4394x; 1.4394x over previous
//
#include <hip/hip_runtime.h>
#include <hip/hip_bf16.h>
#include <cstddef>
#include <cstring>

// ---------------- problem dims (hard-coded from reference) ----------------
constexpr int cB=4, cN=2000, cT=50, cF=10, cD=64, cR=8, cK=16, cE=32;
constexpr int NODES = cB*cN;     // 8000
constexpr int N1    = cN+1;      // 2001 (padded table incl. zero row m=0)
constexpr int ROWS2 = cB*N1;     // 8004

#define DEV static __device__ __forceinline__

typedef __attribute__((ext_vector_type(8))) _Float16 f16x8;   // 8 f16 = 4 VGPR
typedef __attribute__((ext_vector_type(4))) float    f32x4;
typedef __attribute__((ext_vector_type(4))) int      i32x4;

DEV float leaky(float x){ return fmaxf(x, 0.2f*x); }
DEV float wsumall(float v){           // butterfly all-reduce over 64 lanes
  v += __shfl_xor(v,32,64); v += __shfl_xor(v,16,64); v += __shfl_xor(v,8,64);
  v += __shfl_xor(v,4,64);  v += __shfl_xor(v,2,64);  v += __shfl_xor(v,1,64);
  return v;
}
DEV unsigned fu(float f){ return __float_as_uint(f); }
DEV unsigned rne16(float f){                      // RNE bf16 bits of f
  unsigned u = fu(f);
  return (u + 0x7FFFu + ((u>>16)&1u)) >> 16;
}
DEV unsigned f16b(float f){                       // f32 -> f16 bits (RNE)
  _Float16 h = (_Float16)f;
  unsigned short u; __builtin_memcpy(&u, &h, 2);
  return (unsigned)u;
}
DEV unsigned f16p(float a, float b){ return f16b(a) | (f16b(b) << 16); }
// u32 = f16(f) | f16(f - f16(f)) << 16   (hi + residual-lo, error ~2^-23)
DEV unsigned pack_hl16(float f){
  _Float16 h = (_Float16)f;
  float r = f - (float)h;
  return f16b(f) | (f16b(r) << 16);
}
// pair low16(x),low16(y) -> one u32 (two hi-f16s)
DEV unsigned PLO(unsigned x, unsigned y){ return __builtin_amdgcn_perm(y, x, 0x05040100u); }
// pair high16(x),high16(y) -> one u32 (two lo-f16s)
DEV unsigned PHI(unsigned x, unsigned y){ return __builtin_amdgcn_perm(y, x, 0x07060302u); }
DEV f16x8 packh(unsigned a, unsigned b, unsigned c2, unsigned d){
  union { i32x4 i; f16x8 h; } u;
  u.i = (i32x4){(int)a,(int)b,(int)c2,(int)d};
  return u.h;
}
DEV f32x4 MF16(f16x8 a, f16x8 b, f32x4 c){
  return __builtin_amdgcn_mfma_f32_16x16x32_f16(a, b, c, 0, 0, 0);
}
DEV float bfu(unsigned short u){ return __uint_as_float(((unsigned)u)<<16); }
DEV float ex2(float x){ float r; asm("v_exp_f32 %0, %1" : "=v"(r) : "v"(x)); return r; }

// ==== K1: GRU (f16 MFMA, R8 structure; h = u32-packed f16 hi|lo, R3/R5 LDS
//      pattern) + fused projection ============================================
// Block = 256 thr = 4 waves over 16 nodes; wave w owns gate d-slice
// [16w,16w+16). h crosses steps in ONE u32 LDS tile sH[2][1024]
// ([node*64+d] ^ ((node&7)<<2)), each u32 = f16(h) | f16(residual)<<16 —
// the exact single-array u32-store + PLO/PHI-unpack pattern that passed in
// R3 and R5 at this geometry (only payload bf16->f16). 15 MFMA/step/wave
// (hi+lo halves). Bias rides a constant-1.0 x-slot (f=10); log2e folded into
// U/W/bias so gates use native v_exp_f32. Step fence = __syncthreads()
// (R13-proven; the vmcnt drain hits a prefetch issued ~a full step earlier).
// The u16-store/two-array variant (R14/R15) is abandoned: NaN'd under both
// fence types at TN=16 while passing at TN=8 — unresolved codegen hazard.
// Epilogue: wave w projects the 16 nodes for r=2w,2w+1 (8 MFMA each, h-hi
// only = f16(h), the same operand R13's k_proj validated at 1.95e-3).
__global__ __launch_bounds__(256, 2) void k_gru(const float* __restrict__ X,
    const float* __restrict__ gW, const float* __restrict__ gU,
    const float* __restrict__ gb, const float* __restrict__ pW,
    const float* __restrict__ pb, const float* __restrict__ sattW,
    float* __restrict__ node, unsigned short* __restrict__ actb,
    float* __restrict__ sng2)
{
  __shared__ unsigned sH[2][1024];   // [buf][node*64 + d] ^ ((node&7)<<2)

  const int tid  = threadIdx.x;
  const int lane = tid & 63;
  const int w    = tid >> 6;            // wave 0..3 -> d-slice / r-pair
  const int c    = lane & 15;
  const int kg   = lane >> 4;
  const int nb   = (int)blockIdx.x * 16;
  const int col  = 16*w + c;            // d-channel this lane produces
  const int bb   = nb / cN;             // batch (block-uniform)

  const float SZ = -1.4426950408889634f;   // -log2(e): z,r gates
  const float SH =  2.8853900817779268f;   // 2*log2(e): h~ gate

  // ---- persistent B fragments (VGPR): U f16 per K-half; W f16 k=2f slots ----
  f16x8 Uf[2][3];
  #pragma unroll
  for (int s=0;s<2;++s){
    #pragma unroll
    for (int cls=0; cls<3; ++cls){
      const float sc = (cls==2) ? SH : SZ;
      const int n = cls*64 + col;
      unsigned wd[4];
      #pragma unroll
      for (int p=0;p<4;++p){
        int d0 = s*32 + kg*8 + 2*p;
        wd[p] = f16p(sc*gU[d0*192 + n], sc*gU[(d0+1)*192 + n]);
      }
      Uf[s][cls] = packh(wd[0],wd[1],wd[2],wd[3]);
    }
  }
  // gate biases (b0+b1 for z/r; bh0 rides x-side; bh1 stays in aHc init)
  const float bzt = SZ*(gb[col] + gb[192+col]);
  const float brt = SZ*(gb[64+col] + gb[256+col]);
  const float bh0 = SH* gb[128+col];
  const float bh1 = SH* gb[320+col];
  f16x8 BXf[3];
  #pragma unroll
  for (int cls=0; cls<3; ++cls){
    const float sc = (cls==2) ? SH : SZ;
    const float bv = (cls==0) ? bzt : (cls==1 ? brt : bh0);
    const int n = cls*64 + col;
    unsigned wd[4];
    #pragma unroll
    for (int p=0;p<4;++p){
      int f = kg*4 + p;
      unsigned v = (f < cF) ? f16b(sc*gW[f*192 + n]) : ((f == cF) ? f16b(bv) : 0u);
      wd[p] = v;                      // hi16 = 0 (odd k-slots multiply zero)
    }
    BXf[cls] = packh(wd[0],wd[1],wd[2],wd[3]);
  }

  // ---- zero h tile (buf 0) ----
  for (int i2 = tid; i2 < 1024; i2 += 256) sH[0][i2] = 0u;
  f32x4 ho = {0.f,0.f,0.f,0.f};
  __syncthreads();

  // ---- x prefetch, 2 steps ahead; f==10 slot carries constant 1.0 (bias) ----
  float xc[4], xn[4];
  const float* Xb = X + (size_t)(nb + c)*cT*cF;
  #pragma unroll
  for (int p=0;p<4;++p){
    int f = 4*kg+p;
    float fill = (f == cF) ? 1.0f : 0.0f;
    xc[p] = (f < cF) ? Xb[0*cF + f] : fill;
    xn[p] = (f < cF) ? Xb[1*cF + f] : fill;
  }

  // ---- hoisted LDS offsets (R3/R5-proven formulas) ----
  const unsigned sw = (unsigned)((c&7)<<2);
  const unsigned oA = ((unsigned)(c*64 + kg*8)) ^ sw;   // d = kg*8 .. +3
  const unsigned oB = oA ^ 4u;                          // d = kg*8+4 .. +7
  const unsigned oC = oA ^ 32u;                         // d = 32+kg*8 .. +3
  const unsigned oD = oA ^ 36u;                         // d = 32+kg*8+4 .. +7
  unsigned wrs[4];
  #pragma unroll
  for (int reg=0; reg<4; ++reg){
    int nodei = kg*4 + reg;
    wrs[reg] = ((unsigned)(nodei*64 + col)) ^ ((unsigned)((nodei&7)<<2));
  }
  const f32x4 zq = {0.f,0.f,0.f,0.f};

  for (int t = 0; t < cT; ++t){
    // ---- x A-fragment (f16 in lo16 of each dword) ----
    f16x8 xf = packh(f16b(xc[0]), f16b(xc[1]), f16b(xc[2]), f16b(xc[3]));
    #pragma unroll
    for (int p=0;p<4;++p) xc[p] = xn[p];
    {
      int tn = (t+2 < cT) ? t+2 : cT-1;
      #pragma unroll
      for (int p=0;p<4;++p){
        int f = 4*kg+p;
        float fill = (f == cF) ? 1.0f : 0.0f;
        xn[p] = (f < cF) ? Xb[(size_t)tn*cF + f] : fill;
      }
    }

    // ---- h A-fragments: 4x b128 reads + PLO/PHI unpack (hi & lo) ----
    const unsigned* sr = sH[t & 1];
    i32x4 qa = *(const i32x4*)(sr + oA);
    i32x4 qb = *(const i32x4*)(sr + oB);
    i32x4 qc = *(const i32x4*)(sr + oC);
    i32x4 qd = *(const i32x4*)(sr + oD);
    f16x8 hah = packh(PLO(qa[0],qa[1]), PLO(qa[2],qa[3]), PLO(qb[0],qb[1]), PLO(qb[2],qb[3]));
    f16x8 hal = packh(PHI(qa[0],qa[1]), PHI(qa[2],qa[3]), PHI(qb[0],qb[1]), PHI(qb[2],qb[3]));
    f16x8 hbh = packh(PLO(qc[0],qc[1]), PLO(qc[2],qc[3]), PLO(qd[0],qd[1]), PLO(qd[2],qd[3]));
    f16x8 hbl = packh(PHI(qc[0],qc[1]), PHI(qc[2],qc[3]), PHI(qd[0],qd[1]), PHI(qd[2],qd[3]));

    // ---- MFMA: 15 per wave (hi half then lo half) ----
    f32x4 aZ  = MF16(xf, BXf[0], zq);
    f32x4 aR  = MF16(xf, BXf[1], zq);
    f32x4 aXh = MF16(xf, BXf[2], zq);
    f32x4 aHc = {bh1,bh1,bh1,bh1};
    aZ  = MF16(hah, Uf[0][0], aZ);  aZ  = MF16(hbh, Uf[1][0], aZ);
    aR  = MF16(hah, Uf[0][1], aR);  aR  = MF16(hbh, Uf[1][1], aR);
    aHc = MF16(hah, Uf[0][2], aHc); aHc = MF16(hbh, Uf[1][2], aHc);
    aZ  = MF16(hal, Uf[0][0], aZ);  aZ  = MF16(hbl, Uf[1][0], aZ);
    aR  = MF16(hal, Uf[0][1], aR);  aR  = MF16(hbl, Uf[1][1], aR);
    aHc = MF16(hal, Uf[0][2], aHc); aHc = MF16(hbl, Uf[1][2], aHc);

    // ---- gates (fp32) -> h packed (f16 hi | f16 lo) as ONE u32 store ----
    unsigned* swr = sH[(t & 1) ^ 1];
    #pragma unroll
    for (int reg=0; reg<4; ++reg){
      float z   = __builtin_amdgcn_rcpf(1.0f + ex2(aZ[reg]));
      float r   = __builtin_amdgcn_rcpf(1.0f + ex2(aR[reg]));
      float phv = __builtin_fmaf(r, aHc[reg], aXh[reg]);
      float th  = __builtin_fmaf(-2.0f, __builtin_amdgcn_rcpf(ex2(phv) + 1.0f), 1.0f);
      float hn  = __builtin_fmaf(z, ho[reg]-th, th);
      ho[reg] = hn;
      swr[wrs[reg]] = pack_hl16(hn);
    }
    // full compiler-respected fence (R13-proven)
    __syncthreads();
  }

  // ---- write out h (fp32) for k_attn ----
  #pragma unroll
  for (int reg=0; reg<4; ++reg)
    node[(size_t)(nb + kg*4 + reg)*cD + col] = ho[reg];

  // ================= fused projection epilogue (f16, h-hi only) =============
  // final h is in sH[0] (t=49 wrote buf 0; __syncthreads passed). h-hi =
  // f16(h) — the operand R13's k_proj validated. lo ~2^-12 < act's bf16
  // storage rounding.
  {
    const unsigned* sr = &sH[0][0];
    i32x4 qa = *(const i32x4*)(sr + oA);
    i32x4 qb = *(const i32x4*)(sr + oB);
    i32x4 qc = *(const i32x4*)(sr + oC);
    i32x4 qd = *(const i32x4*)(sr + oD);
    f16x8 ha = packh(PLO(qa[0],qa[1]), PLO(qa[2],qa[3]), PLO(qb[0],qb[1]), PLO(qb[2],qb[3]));
    f16x8 hb = packh(PLO(qc[0],qc[1]), PLO(qc[2],qc[3]), PLO(qd[0],qd[1]), PLO(qd[2],qd[3]));

    const int qbase = nb + bb + 1;        // padded-table row of node nb
    #pragma unroll
    for (int rr=0; rr<2; ++rr){
      const int r = 2*w + rr;
      const float* Pr = pW + (size_t)r*cD*cD;
      f16x8 PB[4][2];
      float pbv[4], wnv[4];
      #pragma unroll
      for (int cb=0; cb<4; ++cb){
        const int e = 16*cb + c;
        #pragma unroll
        for (int s2=0;s2<2;++s2){
          unsigned wd[4];
          #pragma unroll
          for (int p=0;p<4;++p){
            int d0 = s2*32 + kg*8 + 2*p;
            wd[p] = f16p(Pr[(size_t)d0*cD + e], Pr[(size_t)(d0+1)*cD + e]);
          }
          PB[cb][s2] = packh(wd[0],wd[1],wd[2],wd[3]);
        }
        pbv[cb] = pb[r*cD + e];
        wnv[cb] = sattW[r*(2*cD+cE) + cD + e];
      }
      float sp[4] = {0.f,0.f,0.f,0.f};
      #pragma unroll
      for (int cb=0; cb<4; ++cb){
        f32x4 acc = {pbv[cb],pbv[cb],pbv[cb],pbv[cb]};
        acc = MF16(ha, PB[cb][0], acc);
        acc = MF16(hb, PB[cb][1], acc);
        #pragma unroll
        for (int reg=0; reg<4; ++reg){
          float o = leaky(acc[reg]);
          int qrow = qbase + kg*4 + reg;
          actb[((size_t)r*ROWS2 + qrow)*cD + 16*cb + c] = (unsigned short)rne16(o);
          sp[reg] = __builtin_fmaf(o, wnv[cb], sp[reg]);
        }
      }
      #pragma unroll
      for (int reg=0; reg<4; ++reg){
        float s2 = sp[reg];
        s2 += __shfl_xor(s2,1,64); s2 += __shfl_xor(s2,2,64);
        s2 += __shfl_xor(s2,4,64); s2 += __shfl_xor(s2,8,64);
        if (c == 0) sng2[(size_t)r*ROWS2 + qbase + kg*4 + reg] = s2;
      }
    }
  }

  // ---- 4 designated blocks write the m=0 (zero-input) rows ----
  if ((blockIdx.x % (cN/16)) == 0){
    #pragma unroll
    for (int rr=0; rr<2; ++rr){
      const int r = 2*w + rr;
      float v0 = leaky(pb[r*cD + lane]);
      float wv = sattW[r*(2*cD+cE) + cD + lane];
      actb[((size_t)r*ROWS2 + (size_t)bb*N1)*cD + lane] = (unsigned short)rne16(v0);
      float s2 = wsumall(v0 * wv);
      if (lane == 0) sng2[(size_t)r*ROWS2 + (size_t)bb*N1] = s2;
    }
  }
}

// ============ K3: fused attention + head (+ per-r scalars), 1 wave/(b,n) ==
__global__ __launch_bounds__(256) void k_attn(const float* __restrict__ node,
    const int* __restrict__ nbrs, const float* __restrict__ sattW,
    const float* __restrict__ sattb, const float* __restrict__ rattW,
    const float* __restrict__ rattb, const float* __restrict__ predW,
    const float* __restrict__ predb, const float* __restrict__ relemb,
    const unsigned short* __restrict__ actb, const float* __restrict__ sng2,
    float* __restrict__ out)
{
  __shared__ float sSA[cR][cD];        // w_cur rows
  __shared__ float sSrel[cR], sRremb[cR];
  __shared__ float sAtt[4][cR][cK];
  __shared__ int   sOff[4][cR][cK];
  const int tid = threadIdx.x;
  for (int i=tid; i<cR*cD; i+=256) sSA[i>>6][i&63] = sattW[(i>>6)*(2*cD+cE) + (i&63)];
  if (tid < 64){                       // per-r scalars: srel, rremb
    int r = tid >> 3, j0 = (tid & 7)*4;
    float a = 0.f, b2 = 0.f;
    #pragma unroll
    for (int j=0;j<4;++j){
      float re = relemb[r*cE + j0 + j];
      a  += re * sattW[r*(2*cD+cE) + 2*cD + j0 + j];
      b2 += re * rattW[2*cD + j0 + j];
    }
    a  += __shfl_xor(a,1,64);  a  += __shfl_xor(a,2,64);  a  += __shfl_xor(a,4,64);
    b2 += __shfl_xor(b2,1,64); b2 += __shfl_xor(b2,2,64); b2 += __shfl_xor(b2,4,64);
    if ((tid & 7) == 0){ sSrel[r] = a + sattb[r]; sRremb[r] = b2; }
  }
  __syncthreads();

  const int wave = tid >> 6, lane = tid & 63;
  const int gn = (int)blockIdx.x*4 + wave;          // 0..7999
  const int b = __builtin_amdgcn_readfirstlane(gn / cN);
  const int n = __builtin_amdgcn_readfirstlane(gn % cN);

  const float cur = node[(size_t)gn*cD + lane];

  float scr[8];
  #pragma unroll
  for (int r=0; r<8; ++r) scr[r] = wsumall(cur * sSA[r][lane]);

  const int g = lane >> 4, k = lane & 15;
  #pragma unroll
  for (int half=0; half<2; ++half){
    int r = half*4 + g;
    float sc0 = half==0 ? (g==0?scr[0]:g==1?scr[1]:g==2?scr[2]:scr[3])
                        : (g==0?scr[4]:g==1?scr[5]:g==2?scr[6]:scr[7]);
    int idx = nbrs[(((size_t)b*cR + r)*cN + n)*cK + k];
    int o = r*ROWS2 + b*N1 + idx;
    float sv = sng2[o];
    float sc = leaky(sc0 + sv + sSrel[r]);
    if (idx == 0) sc -= 1e9f;
    float mx = sc;
    mx = fmaxf(mx, __shfl_xor(mx,1,64)); mx = fmaxf(mx, __shfl_xor(mx,2,64));
    mx = fmaxf(mx, __shfl_xor(mx,4,64)); mx = fmaxf(mx, __shfl_xor(mx,8,64));
    float ex = __expf(sc - mx);
    float sm = ex;
    sm += __shfl_xor(sm,1,64); sm += __shfl_xor(sm,2,64);
    sm += __shfl_xor(sm,4,64); sm += __shfl_xor(sm,8,64);
    sAtt[wave][r][k] = ex/sm;
    sOff[wave][r][k] = o;
  }
  __syncthreads();

  float facc[8];
  #pragma unroll
  for (int r=0; r<8; ++r){
    float a0=0.f, a1=0.f;
    #pragma unroll
    for (int kk=0; kk<cK; kk+=2){
      float w0 = sAtt[wave][r][kk],   w1 = sAtt[wave][r][kk+1];
      int   o0 = sOff[wave][r][kk],   o1 = sOff[wave][r][kk+1];
      a0 += w0 * bfu(actb[(size_t)o0*cD + lane]);
      a1 += w1 * bfu(actb[(size_t)o1*cD + lane]);
    }
    facc[r] = a0 + a1;
  }

  const float rcur = rattW[lane], rrep = rattW[cD + lane];
  const float rb   = rattb[0];
  const float c0 = wsumall(cur * rcur);
  float rs[8];
  #pragma unroll
  for (int r=0; r<8; ++r) rs[r] = leaky(c0 + wsumall(facc[r]*rrep) + sRremb[r] + rb);
  float mx = rs[0];
  #pragma unroll
  for (int r=1; r<8; ++r) mx = fmaxf(mx, rs[r]);
  float es = 0.f; float ratt[8];
  #pragma unroll
  for (int r=0; r<8; ++r){ ratt[r] = __expf(rs[r]-mx); es += ratt[r]; }
  float inv = 1.f/es;
  float agg = 0.f;
  #pragma unroll
  for (int r=0; r<8; ++r) agg += (ratt[r]*inv) * facc[r];
  const float upd = cur + agg;

  float l0 = wsumall(upd * predW[lane*3 + 0]);
  float l1 = wsumall(upd * predW[lane*3 + 1]);
  float l2 = wsumall(upd * predW[lane*3 + 2]);
  if (lane == 0){
    l0 += predb[0]; l1 += predb[1]; l2 += predb[2];
    float m2 = fmaxf(l0, fmaxf(l1, l2));
    float e0 = __expf(l0-m2), e1 = __expf(l1-m2), e2 = __expf(l2-m2);
    float is = 1.f/(e0+e1+e2);
    out[(size_t)gn*3+0] = e0*is;
    out[(size_t)gn*3+1] = e1*is;
    out[(size_t)gn*3+2] = e2*is;
  }
}

// ================================ launch =================================
extern "C" void kernel_launch(void* const* d_in, const int* in_sizes, int n_in,
                              void* d_out, int out_size, void* d_ws, size_t ws_size,
                              hipStream_t stream)
{
  const float* X      = (const float*)d_in[0];
  const int*   nbrs   = (const int*)  d_in[1];
  const float* gW     = (const float*)d_in[2];
  const float* gU     = (const float*)d_in[3];
  const float* gb     = (const float*)d_in[4];
  const float* relemb = (const float*)d_in[5];
  const float* pW     = (const float*)d_in[6];
  const float* pb     = (const float*)d_in[7];
  const float* sattW  = (const float*)d_in[8];
  const float* sattb  = (const float*)d_in[9];
  const float* rattW  = (const float*)d_in[10];
  const float* rattb  = (const float*)d_in[11];
  const float* predW  = (const float*)d_in[12];
  const float* predb  = (const float*)d_in[13];
  float* out = (float*)d_out;

  // workspace: node fp32 | act bf16 (r-major) | sng fp32
  float*          node  = (float*)d_ws;                                 // NODES*cD
  unsigned short* actb  = (unsigned short*)(node + (size_t)NODES*cD);   // cR*ROWS2*cD bf16
  float*          sng2  = (float*)(actb + (size_t)cR*ROWS2*cD);         // cR*ROWS2

  k_gru <<<NODES/16, 256, 0, stream>>>(X, gW, gU, gb, pW, pb, sattW,
                                       node, actb, sng2);
  k_attn<<<NODES/4, 256, 0, stream>>>(node, nbrs, sattW, sattb, rattW, rattb,
                                      predW, predb, relemb, actb, sng2, out);
}